// Round 1
// 532.492 us; speedup vs baseline: 1.0198x; 1.0198x over previous
//
#include <hip/hip_runtime.h>

#define B_ 64
#define T_ 512
#define D_ 1024
#define C_ 32
#define NEG_INF (-1e30f)

__device__ __forceinline__ float bcast0(float v) {
  return __uint_as_float(__builtin_amdgcn_readfirstlane(__float_as_uint(v)));
}

// ---------------- logits = vectors @ W^T + b (f32, sequential-k fma chain) ----------------
// grid 256, block 256. Block tile: 128 rows x 32 cols. Thread: 4 rows (stride 32) x 4 cols (stride 8).
// Single f32 accumulator per output, k ascending: mirrors a sequential np einsum
// so logit rounding correlates with (and mostly cancels against) the np reference's.
__global__ __launch_bounds__(256) void k_logits(const float* __restrict__ vec,
                                                const float* __restrict__ W,
                                                const float* __restrict__ bias,
                                                float* __restrict__ out) {
  const int tid = threadIdx.x;
  const int cg = tid & 7;   // col base 0..7  (cols cg + 8*cc)
  const int rg = tid >> 3;  // 0..31          (rows r0 + rg + 32*rr)
  const int r0 = blockIdx.x * 128;
  float acc[4][4];
#pragma unroll
  for (int a = 0; a < 4; ++a)
#pragma unroll
    for (int bb = 0; bb < 4; ++bb) acc[a][bb] = 0.f;
  const float* vb = vec + (size_t)(r0 + rg) * D_;
  const float* wb = W + (size_t)cg * D_;
#pragma unroll 4
  for (int k = 0; k < D_; k += 4) {
    float4 v[4], w[4];
#pragma unroll
    for (int rr = 0; rr < 4; ++rr) v[rr] = *(const float4*)(vb + (size_t)rr * 32 * D_ + k);
#pragma unroll
    for (int cc = 0; cc < 4; ++cc) w[cc] = *(const float4*)(wb + (size_t)cc * 8 * D_ + k);
#pragma unroll
    for (int rr = 0; rr < 4; ++rr)
#pragma unroll
      for (int cc = 0; cc < 4; ++cc) {
        acc[rr][cc] = fmaf(v[rr].x, w[cc].x, acc[rr][cc]);
        acc[rr][cc] = fmaf(v[rr].y, w[cc].y, acc[rr][cc]);
        acc[rr][cc] = fmaf(v[rr].z, w[cc].z, acc[rr][cc]);
        acc[rr][cc] = fmaf(v[rr].w, w[cc].w, acc[rr][cc]);
      }
  }
#pragma unroll
  for (int rr = 0; rr < 4; ++rr) {
    const size_t row = (size_t)(r0 + rg + rr * 32);
#pragma unroll
    for (int cc = 0; cc < 4; ++cc) {
      const int c = cg + cc * 8;
      out[row * C_ + c] = acc[rr][cc] + bias[c];  // b32 store: out base only 4B-aligned
    }
  }
}

// ---------------- CRF: forward(+score) and Viterbi(+backtrace) ----------------
// grid 128 x 64 threads (one wave64 per block -> LDS in-order, no barriers;
// validated by R3==R4 tag equality).
// blocks 0..63: forward logsumexp + logZ + gold score (f32).
// blocks 64..127: f32 Viterbi — every add/max/argmax is an elementwise f32 op,
// bit-replicating a float32 numpy reference DP. First-index tie-breaks throughout.
//
// R5: latency fix. The serial T-loop was ~1005 cyc/iter; ~600 of that was the
// exposed per-step global fetch of the logits row (one-iteration register
// prefetch only hides ~350 cyc of the ~900-cyc HBM/L2-remote latency).
// Logits rows are now staged into LDS in double-buffered 64-row chunks
// (prefetch distance = 64 iterations), and the mask is preloaded to LDS once.
// Staging loads are SCALAR b32 on purpose: logits = out+1 is only 4B-aligned,
// so float4 loads from L would be UB. All values read are bit-identical to the
// previous version; every arithmetic op and tie-break is unchanged.
__global__ __launch_bounds__(64) void k_crf(const float* __restrict__ lg,
                                            const int* __restrict__ mask,
                                            const int* __restrict__ tgt,
                                            const float* __restrict__ trans,
                                            const float* __restrict__ st,
                                            const float* __restrict__ et,
                                            float* __restrict__ wsp,
                                            float* __restrict__ tags_out,
                                            float* __restrict__ path_out) {
  __shared__ __align__(16) float a_sh[C_];
  __shared__ __align__(16) float f_sh[C_];
  __shared__ __align__(16) float Lsh[2][64 * C_];  // double-buffered 64-row logits chunks
  __shared__ int mk_sh[T_];
  __shared__ unsigned char bp[(T_ - 1) * C_];
  __shared__ unsigned char tagb[T_];
  __shared__ unsigned char c8[64 * C_];
  __shared__ int btag[64];

  const int tid = threadIdx.x;
  const int b = blockIdx.x & 63;
  const int role = blockIdx.x >> 6;
  const int j = tid & 31;
  const int h = tid >> 5;  // half: i-range [16h, 16h+16)
  const float* L = lg + (size_t)b * T_ * C_;
  const int* mk = mask + b * T_;

  // ---- stage chunk 0 (rows 0..63) + full mask into LDS ----
  float pre[32];
#pragma unroll
  for (int i = 0; i < 32; ++i) pre[i] = L[i * 64 + tid];
  {
    int4 m0 = *(const int4*)(mk + tid * 4);
    int4 m1 = *(const int4*)(mk + 256 + tid * 4);
    *(int4*)&mk_sh[tid * 4] = m0;
    *(int4*)&mk_sh[256 + tid * 4] = m1;
  }
#pragma unroll
  for (int i = 0; i < 32; ++i) Lsh[0][i * 64 + tid] = pre[i];

  if (role == 0) {
    // ================= forward + score =================
    float ET[16];
#pragma unroll
    for (int i = 0; i < 16; ++i) ET[i] = __expf(trans[(h * 16 + i) * C_ + j]);
    float alpha = (tid < 32) ? (st[j] + Lsh[0][j]) : NEG_INF;
    for (int c = 0; c < 8; ++c) {
      if (c < 7) {  // issue next chunk's loads before computing this chunk
#pragma unroll
        for (int i = 0; i < 32; ++i) pre[i] = L[(c + 1) * 2048 + i * 64 + tid];
      }
      const float* Ls = Lsh[c & 1];
      const int tlo = c ? c * 64 : 1;
      const int thi = c * 64 + 64;
      for (int t = tlo; t < thi; ++t) {
        const float lc = Ls[(t - c * 64) * C_ + j];
        const int mc = mk_sh[t];
        const float mhat = bcast0(alpha);
        const float av = __expf(alpha - mhat);
        if (tid < 32) a_sh[j] = av;
        float4 a0 = *(const float4*)&a_sh[h * 16 + 0];
        float4 a1 = *(const float4*)&a_sh[h * 16 + 4];
        float4 a2 = *(const float4*)&a_sh[h * 16 + 8];
        float4 a3 = *(const float4*)&a_sh[h * 16 + 12];
        float s0 = a0.x * ET[0], s1 = a0.y * ET[1], s2 = a0.z * ET[2], s3 = a0.w * ET[3];
        s0 = fmaf(a1.x, ET[4], s0);  s1 = fmaf(a1.y, ET[5], s1);
        s2 = fmaf(a1.z, ET[6], s2);  s3 = fmaf(a1.w, ET[7], s3);
        s0 = fmaf(a2.x, ET[8], s0);  s1 = fmaf(a2.y, ET[9], s1);
        s2 = fmaf(a2.z, ET[10], s2); s3 = fmaf(a2.w, ET[11], s3);
        s0 = fmaf(a3.x, ET[12], s0); s1 = fmaf(a3.y, ET[13], s1);
        s2 = fmaf(a3.z, ET[14], s2); s3 = fmaf(a3.w, ET[15], s3);
        float sp = (s0 + s1) + (s2 + s3);
        sp += __shfl_xor(sp, 32);
        const float anew = mhat + __logf(sp) + lc;
        if (tid < 32 && mc > 0) alpha = anew;
      }
      if (c < 7) {
#pragma unroll
        for (int i = 0; i < 32; ++i) Lsh[(c & 1) ^ 1][i * 64 + tid] = pre[i];
      }
    }
    float val = (tid < 32) ? (alpha + et[j]) : NEG_INF;
    float mm = val;
#pragma unroll
    for (int d = 32; d; d >>= 1) mm = fmaxf(mm, __shfl_xor(mm, d));
    float ee = __expf(val - mm);
#pragma unroll
    for (int d = 32; d; d >>= 1) ee += __shfl_xor(ee, d);
    const float logZ = mm + __logf(ee);
    float sc = 0.f, msf = 0.f;
#pragma unroll
    for (int kk = 0; kk < 8; ++kk) {
      const int t = tid + kk * 64;
      const float mf = (float)mk_sh[t];
      const int tg = tgt[b * T_ + t];
      msf += mf;
      float contrib = 0.f;
      if (t >= 1) contrib += trans[tgt[b * T_ + t - 1] * C_ + tg];
      if (t <= T_ - 2) contrib += L[t * C_ + tg];
      sc = fmaf(mf, contrib, sc);
    }
#pragma unroll
    for (int d = 32; d; d >>= 1) { sc += __shfl_xor(sc, d); msf += __shfl_xor(msf, d); }
    if (tid == 0) {
      int last_idx = (int)msf - 1;
      if (last_idx < 0) last_idx = 0;
      const int lt = tgt[b * T_ + last_idx];
      float s = sc + st[tgt[b * T_]] + et[lt];
      s = fmaf((float)mk_sh[T_ - 1], L[(T_ - 1) * C_ + lt], s);
      wsp[b] = logZ;
      wsp[64 + b] = s;
      wsp[128 + b] = msf;
    }
  } else {
    // ================= Viterbi (f32, np-f32-bit-replicating) =================
    float TT[16];
#pragma unroll
    for (int i = 0; i < 16; ++i) TT[i] = trans[(h * 16 + i) * C_ + j];
    float dj = st[j] + Lsh[0][j];
    if (tid < 32) f_sh[j] = dj;
    for (int c = 0; c < 8; ++c) {
      if (c < 7) {
#pragma unroll
        for (int i = 0; i < 32; ++i) pre[i] = L[(c + 1) * 2048 + i * 64 + tid];
      }
      const float* Ls = Lsh[c & 1];
      const int tlo = c ? c * 64 : 1;
      const int thi = c * 64 + 64;
      for (int t = tlo; t < thi; ++t) {
        const float lc = Ls[(t - c * 64) * C_ + j];
        const int mc = mk_sh[t];
        float dd[16];
        {
          float4 q0 = *(const float4*)&f_sh[h * 16 + 0];
          float4 q1 = *(const float4*)&f_sh[h * 16 + 4];
          float4 q2 = *(const float4*)&f_sh[h * 16 + 8];
          float4 q3 = *(const float4*)&f_sh[h * 16 + 12];
          dd[0] = q0.x;  dd[1] = q0.y;  dd[2] = q0.z;  dd[3] = q0.w;
          dd[4] = q1.x;  dd[5] = q1.y;  dd[6] = q1.z;  dd[7] = q1.w;
          dd[8] = q2.x;  dd[9] = q2.y;  dd[10] = q2.z; dd[11] = q2.w;
          dd[12] = q3.x; dd[13] = q3.y; dd[14] = q3.z; dd[15] = q3.w;
        }
        // plain f32 add (NOT fma): matches np's inner = delta + trans rounding.
        // 4 interleaved chains, ascending indices; strict '>' + index guards
        // preserve exact np.argmax first-index semantics under f32 ties.
        float v0 = dd[0] + TT[0]; int i0 = 0;
        float v1 = dd[1] + TT[1]; int i1 = 1;
        float v2 = dd[2] + TT[2]; int i2 = 2;
        float v3 = dd[3] + TT[3]; int i3 = 3;
#pragma unroll
        for (int q = 1; q < 4; ++q) {
          float c0 = dd[q * 4 + 0] + TT[q * 4 + 0]; if (c0 > v0) { v0 = c0; i0 = q * 4 + 0; }
          float c1 = dd[q * 4 + 1] + TT[q * 4 + 1]; if (c1 > v1) { v1 = c1; i1 = q * 4 + 1; }
          float c2 = dd[q * 4 + 2] + TT[q * 4 + 2]; if (c2 > v2) { v2 = c2; i2 = q * 4 + 2; }
          float c3 = dd[q * 4 + 3] + TT[q * 4 + 3]; if (c3 > v3) { v3 = c3; i3 = q * 4 + 3; }
        }
        if (v1 > v0 || (v1 == v0 && i1 < i0)) { v0 = v1; i0 = i1; }
        if (v3 > v2 || (v3 == v2 && i3 < i2)) { v2 = v3; i2 = i3; }
        if (v2 > v0 || (v2 == v0 && i2 < i0)) { v0 = v2; i0 = i2; }
        int big = h * 16 + i0;
        const float ov = __shfl_xor(v0, 32);
        const int oi = __shfl_xor(big, 32);
        if (ov > v0 || (ov == v0 && oi < big)) { v0 = ov; big = oi; }
        if (tid < 32) {
          int bpv = j;
          if (mc > 0) { dj = v0 + lc; bpv = big; }  // f32 add: matches np best+lt
          bp[(t - 1) * C_ + j] = (unsigned char)bpv;
          f_sh[j] = dj;
        }
      }
      if (c < 7) {
#pragma unroll
        for (int i = 0; i < 32; ++i) Lsh[(c & 1) ^ 1][i * 64 + tid] = pre[i];
      }
    }
    // final argmax (first-index tie-break) + path score — f32 elementwise
    float fv = (tid < 32) ? (dj + et[j]) : NEG_INF;
    int fi = (tid < 32) ? j : 64;
#pragma unroll
    for (int d = 32; d; d >>= 1) {
      const float ov = __shfl_xor(fv, d);
      const int oi = __shfl_xor(fi, d);
      if (ov > fv || (ov == fv && oi < fi)) { fv = ov; fi = oi; }
    }
    const int last_tag = fi;
    if (tid == 0) path_out[b] = fv;
    // ---- backtrace: 8-step jump maps (validated: R3==R4 tag equality) ----
    int cur[32];
#pragma unroll
    for (int e = 0; e < 32; ++e) cur[e] = (tid + 64 * e) & 31;
#pragma unroll
    for (int s = 0; s < 8; ++s) {
#pragma unroll
      for (int e = 0; e < 32; ++e) {
        const int m = (tid + 64 * e) >> 5;
        const int r = 8 * m + 7 - s;
        if (r <= T_ - 2) cur[e] = bp[r * C_ + cur[e]];
      }
    }
#pragma unroll
    for (int e = 0; e < 32; ++e) c8[tid + 64 * e] = (unsigned char)cur[e];
    if (tid == 0) {
      int c = last_tag;
      tagb[T_ - 1] = (unsigned char)c;
      for (int m = 63; m >= 0; --m) { c = c8[m * C_ + c]; btag[m] = c; }  // btag[m]=tag_{8m}
    }
    {
      const int m = tid;
      const int rhi = (m == 63) ? (T_ - 2) : (8 * m + 7);
      int c = (m == 63) ? last_tag : btag[m + 1];
#pragma unroll
      for (int s = 0; s < 7; ++s) {
        const int r = rhi - s;
        if (r >= 8 * m + 1) { c = bp[r * C_ + c]; tagb[r] = (unsigned char)c; }
      }
      tagb[8 * m] = (unsigned char)btag[m];
    }
#pragma unroll
    for (int kk = 0; kk < 8; ++kk) {
      const int t = tid + kk * 64;
      tags_out[b * T_ + t] = (float)tagb[t];
    }
  }
}

// ---------------- loss reduction ----------------
__global__ __launch_bounds__(64) void k_loss(const float* __restrict__ wsp, float* __restrict__ out0) {
  const int tid = threadIdx.x;
  float d = wsp[64 + tid] - wsp[tid];
  float m = wsp[128 + tid];
#pragma unroll
  for (int s = 32; s; s >>= 1) { d += __shfl_xor(d, s); m += __shfl_xor(m, s); }
  if (tid == 0) out0[0] = -d / m;
}

extern "C" void kernel_launch(void* const* d_in, const int* in_sizes, int n_in,
                              void* d_out, int out_size, void* d_ws, size_t ws_size,
                              hipStream_t stream) {
  (void)in_sizes; (void)n_in; (void)out_size; (void)ws_size;
  const float* vec  = (const float*)d_in[0];
  const int* mask   = (const int*)d_in[1];
  const int* tgt    = (const int*)d_in[2];
  const float* W    = (const float*)d_in[3];
  const float* bias = (const float*)d_in[4];
  const float* tr   = (const float*)d_in[5];
  const float* st   = (const float*)d_in[6];
  const float* et   = (const float*)d_in[7];
  float* out = (float*)d_out;
  float* logits = out + 1;
  float* tags = out + 1 + (size_t)B_ * T_ * C_;
  float* path = tags + (size_t)B_ * T_;
  float* wsp = (float*)d_ws;  // [0,64): logZ  [64,128): score  [128,192): mask-sum

  hipLaunchKernelGGL(k_logits, dim3(256), dim3(256), 0, stream, vec, W, bias, logits);
  hipLaunchKernelGGL(k_crf, dim3(128), dim3(64), 0, stream, logits, mask, tgt, tr, st, et, wsp, tags, path);
  hipLaunchKernelGGL(k_loss, dim3(1), dim3(64), 0, stream, wsp, out);
}